// Round 4
// baseline (273.859 us; speedup 1.0000x reference)
//
#include <hip/hip_runtime.h>
#include <hip/hip_bf16.h>

#define NPTS  20000
#define DIM   128
#define NA    1024
#define NTASK 2048
#define G     8        // tasks per dist block
#define P     4        // points per thread
#define TILE  1024     // P * 256 points per dist block
#define KSEL  50
#define GAMMA 1.0f
#define CBIN  128      // coarse bins: d>>8, d <= 128*255 = 32640
#define CAP   4096

typedef unsigned char  u8t;
typedef unsigned short u16t;

static __device__ __forceinline__ unsigned sad8(unsigned a, unsigned b, unsigned c) {
#if __has_builtin(__builtin_amdgcn_sad_u8)
    return __builtin_amdgcn_sad_u8(a, b, c);
#else
    unsigned d;
    asm("v_sad_u8 %0, %1, %2, %3" : "=v"(d) : "v"(a), "v"(b), "v"(c));
    return d;
#endif
}

__global__ __launch_bounds__(256) void init_kernel(float* out, unsigned* ghist, unsigned* gmax) {
    const int i = (int)blockIdx.x * 256 + (int)threadIdx.x;
    const int nt = (int)gridDim.x * 256;
    for (int j = i; j < NTASK * CBIN; j += nt) ghist[j] = 0u;
    if (i == 0) { out[0] = 0.0f; gmax[0] = 0u; }
}

__global__ __launch_bounds__(256) void maxabs_kernel(
    const float* __restrict__ o1, const float* __restrict__ o2,
    unsigned* __restrict__ gmax)
{
    const int nt = (int)gridDim.x * 256;
    const float4* a = (const float4*)o1;
    const float4* b = (const float4*)o2;
    float m = 0.0f;
    for (int i = (int)blockIdx.x * 256 + (int)threadIdx.x; i < NPTS * DIM / 4; i += nt) {
        const float4 x = a[i], y = b[i];
        m = fmaxf(m, fmaxf(fmaxf(fabsf(x.x), fabsf(x.y)), fmaxf(fabsf(x.z), fabsf(x.w))));
        m = fmaxf(m, fmaxf(fmaxf(fabsf(y.x), fabsf(y.y)), fmaxf(fabsf(y.z), fabsf(y.w))));
    }
    #pragma unroll
    for (int off = 32; off >= 1; off >>= 1) m = fmaxf(m, __shfl_xor(m, off));
    if ((threadIdx.x & 63) == 0) atomicMax(gmax, __float_as_uint(m));  // m >= 0: bit order == float order
}

__global__ __launch_bounds__(256) void quant_kernel(
    const float* __restrict__ o1, const float* __restrict__ o2,
    u8t* __restrict__ q1, u8t* __restrict__ q2,
    const unsigned* __restrict__ gmax)
{
    const float M = __uint_as_float(*gmax);
    const float s = 255.0f / (2.0f * M);
    const int nt = (int)gridDim.x * 256;
    const float4* a = (const float4*)o1;
    const float4* b = (const float4*)o2;
    unsigned* qa = (unsigned*)q1;
    unsigned* qb = (unsigned*)q2;
    for (int i = (int)blockIdx.x * 256 + (int)threadIdx.x; i < NPTS * DIM / 4; i += nt) {
        const float4 x = a[i];
        unsigned u0 = __float2uint_rn((x.x + M) * s); if (u0 > 255u) u0 = 255u;
        unsigned u1 = __float2uint_rn((x.y + M) * s); if (u1 > 255u) u1 = 255u;
        unsigned u2 = __float2uint_rn((x.z + M) * s); if (u2 > 255u) u2 = 255u;
        unsigned u3 = __float2uint_rn((x.w + M) * s); if (u3 > 255u) u3 = 255u;
        qa[i] = u0 | (u1 << 8) | (u2 << 16) | (u3 << 24);
        const float4 y = b[i];
        unsigned v0 = __float2uint_rn((y.x + M) * s); if (v0 > 255u) v0 = 255u;
        unsigned v1 = __float2uint_rn((y.y + M) * s); if (v1 > 255u) v1 = 255u;
        unsigned v2 = __float2uint_rn((y.z + M) * s); if (v2 > 255u) v2 = 255u;
        unsigned v3 = __float2uint_rn((y.w + M) * s); if (v3 > 255u) v3 = 255u;
        qb[i] = v0 | (v1 << 8) | (v2 << 16) | (v3 << 24);
    }
}

// L1 distances via v_sad_u8 for G tasks x TILE points; writes exact u16
// distances + fused per-task coarse histogram (bin = d>>8) to global.
__global__ __launch_bounds__(256) void dist_kernel(
    const u8t* __restrict__ q1, const u8t* __restrict__ q2,
    const int* __restrict__ anchor1, const int* __restrict__ anchor2,
    u16t* __restrict__ wsd, unsigned* __restrict__ ghist, int chunk_start)
{
    __shared__ uint4 sa[G][8];            // 8 tasks x 128 u8 = 1 KB
    __shared__ unsigned shist[G][CBIN];   // 4 KB

    const int tid = threadIdx.x;
    const int t0 = chunk_start + (int)blockIdx.x * G;

    for (int i = tid; i < G * CBIN; i += 256) ((unsigned*)shist)[i] = 0u;
    if (tid < G * 8) {
        const int g = tid >> 3, c = tid & 7;
        const int t = t0 + g;
        int row; const u8t* src;
        if (t < NA) { row = anchor1[t];      src = q1; }
        else        { row = anchor2[t - NA]; src = q2; }
        sa[g][c] = ((const uint4*)(src + (size_t)row * DIM))[c];
    }
    __syncthreads();

    const u8t* baseq = (t0 < NA) ? q2 : q1;
    const int n0 = (int)blockIdx.y * TILE + tid * P;
    const bool valid = (n0 < NPTS);                 // n0 multiple of 4, NPTS%4==0
    const int nc = valid ? n0 : (NPTS - P);
    const uint4* rp = (const uint4*)(baseq + (size_t)nc * DIM);  // 4 rows x 8 uint4, contiguous

    unsigned acc[P][G];
    #pragma unroll
    for (int p = 0; p < P; ++p)
        #pragma unroll
        for (int g = 0; g < G; ++g) acc[p][g] = 0u;

    uint4 pt[P];
    #pragma unroll
    for (int p = 0; p < P; ++p) pt[p] = rp[p * 8];

    for (int c = 0; c < 8; ++c) {
        uint4 nx[P];
        if (c < 7) {
            #pragma unroll
            for (int p = 0; p < P; ++p) nx[p] = rp[p * 8 + c + 1];
        } else {
            #pragma unroll
            for (int p = 0; p < P; ++p) nx[p] = pt[p];
        }
        #pragma unroll
        for (int g = 0; g < G; ++g) {
            const uint4 s = sa[g][c];
            #pragma unroll
            for (int p = 0; p < P; ++p) {
                unsigned a = acc[p][g];
                a = sad8(pt[p].x, s.x, a);
                a = sad8(pt[p].y, s.y, a);
                a = sad8(pt[p].z, s.z, a);
                a = sad8(pt[p].w, s.w, a);
                acc[p][g] = a;
            }
        }
        #pragma unroll
        for (int p = 0; p < P; ++p) pt[p] = nx[p];
    }

    if (valid) {
        #pragma unroll
        for (int g = 0; g < G; ++g) {
            uint2 w;
            w.x = acc[0][g] | (acc[1][g] << 16);
            w.y = acc[2][g] | (acc[3][g] << 16);
            *(uint2*)(wsd + (size_t)(t0 - chunk_start + g) * NPTS + n0) = w;
            #pragma unroll
            for (int p = 0; p < P; ++p)
                atomicAdd(&shist[g][acc[p][g] >> 8], 1u);
        }
    }
    __syncthreads();

    // sparse flush (most of the 1024 counters are zero)
    for (int i = tid; i < G * CBIN; i += 256) {
        const unsigned v = ((unsigned*)shist)[i];
        if (v) atomicAdd(&ghist[(size_t)(t0 + (i >> 7)) * CBIN + (i & (CBIN - 1))], v);
    }
}

// One block per task: read 128-bin global histogram -> kth coarse bin; ONE
// pass over the u16 row sums relu below the bin and collects kth-bin
// candidates; exact kth via one 256-bin count over the low byte.
__global__ __launch_bounds__(256) void select_kernel(
    const float* __restrict__ o1, const float* __restrict__ o2,
    const int* __restrict__ anchor1, const int* __restrict__ anchor2,
    const u16t* __restrict__ wsd, const unsigned* __restrict__ ghist,
    const unsigned* __restrict__ gmax, int chunk_start, float* __restrict__ d_out)
{
    __shared__ float red[256];
    __shared__ unsigned ch[CBIN];
    __shared__ unsigned h2[256];
    __shared__ u16t lst[CAP];
    __shared__ unsigned s_kbin, s_rem, s_cnt, s_kth, s_remf;

    const int tid = threadIdx.x;
    const int t = chunk_start + (int)blockIdx.x;
    const u16t* R = wsd + (size_t)blockIdx.x * NPTS;

    // D = pos + GAMMA (exact fp32 from originals)
    const int a = (t < NA) ? t : (t - NA);
    const int i1 = anchor1[a], i2 = anchor2[a];
    float p = 0.0f;
    if (tid < DIM) p = fabsf(o1[(size_t)i1 * DIM + tid] - o2[(size_t)i2 * DIM + tid]);
    red[tid] = p;
    __syncthreads();
    for (int s = 128; s >= 1; s >>= 1) { if (tid < s) red[tid] += red[tid + s]; __syncthreads(); }
    const float D = red[0] + GAMMA;
    __syncthreads();

    const float M = __uint_as_float(*gmax);
    const float dq = 2.0f * M / 255.0f;     // u8-metric count -> float distance

    // kth coarse bin via inclusive scan of the 128-entry histogram
    unsigned hv = 0;
    if (tid < CBIN) { hv = ghist[(size_t)t * CBIN + tid]; ch[tid] = hv; }
    if (tid == 0) s_cnt = 0u;
    __syncthreads();
    for (int off = 1; off < CBIN; off <<= 1) {
        const unsigned v = (tid < CBIN) ? ch[tid] : 0u;
        const unsigned u = (tid >= off && tid < CBIN) ? ch[tid - off] : 0u;
        __syncthreads();
        if (tid < CBIN) ch[tid] = v + u;
        __syncthreads();
    }
    if (tid < CBIN) {
        const unsigned cum = ch[tid], cb = cum - hv;
        if (cb < KSEL && cum >= KSEL) { s_kbin = (unsigned)tid; s_rem = KSEL - cb; }
    }
    __syncthreads();
    const unsigned kbin = s_kbin;
    const unsigned rem0 = s_rem;

    // single pass: relu-sum below kbin + candidate collection in kbin
    float local = 0.0f;
    const uint4* R4 = (const uint4*)R;      // 2500 uint4 (8 u16 each)
    for (int i = tid; i < NPTS / 8; i += 256) {
        const uint4 v = R4[i];
        const unsigned w[4] = {v.x, v.y, v.z, v.w};
        #pragma unroll
        for (int j = 0; j < 4; ++j) {
            #pragma unroll
            for (int h = 0; h < 2; ++h) {
                const unsigned u = h ? (w[j] >> 16) : (w[j] & 0xFFFFu);
                const unsigned b = u >> 8;
                if (b < kbin) {
                    local += fmaxf(D - (float)u * dq, 0.0f);
                } else if (b == kbin) {
                    const unsigned ix = atomicAdd(&s_cnt, 1u);
                    if (ix < CAP) lst[ix] = (u16t)u;
                }
            }
        }
    }
    __syncthreads();
    const unsigned cnt = s_cnt;

    unsigned kth, remf;
    if (cnt <= CAP) {
        // all candidates share top byte kbin -> one low-byte count resolves kth
        h2[tid] = 0u;
        __syncthreads();
        for (int i = tid; i < (int)cnt; i += 256) atomicAdd(&h2[lst[i] & 0xFFu], 1u);
        __syncthreads();
        if (tid == 0) {
            unsigned rem = rem0, b = 0;
            for (;; ++b) { const unsigned c = h2[b]; if (c >= rem) break; rem -= c; }
            s_kth = (kbin << 8) | b; s_remf = rem;
        }
        __syncthreads();
        kth = s_kth; remf = s_remf;
        for (int i = tid; i < (int)cnt; i += 256) {
            const unsigned k = lst[i];
            if (k < kth) local += fmaxf(D - (float)k * dq, 0.0f);
        }
    } else {
        // rare fallback: redo the kbin portion from the row (b<kbin sums in
        // 'local' are still valid)
        h2[tid] = 0u;
        __syncthreads();
        for (int i = tid; i < NPTS; i += 256) {
            const unsigned u = R[i];
            if ((u >> 8) == kbin) atomicAdd(&h2[u & 0xFFu], 1u);
        }
        __syncthreads();
        if (tid == 0) {
            unsigned rem = rem0, b = 0;
            for (;; ++b) { const unsigned c = h2[b]; if (c >= rem) break; rem -= c; }
            s_kth = (kbin << 8) | b; s_remf = rem;
        }
        __syncthreads();
        kth = s_kth; remf = s_remf;
        for (int i = tid; i < NPTS; i += 256) {
            const unsigned u = R[i];
            if ((u >> 8) == kbin && u < kth) local += fmaxf(D - (float)u * dq, 0.0f);
        }
    }

    red[tid] = local;
    __syncthreads();
    for (int s = 128; s >= 1; s >>= 1) { if (tid < s) red[tid] += red[tid + s]; __syncthreads(); }
    if (tid == 0) {
        const float total = red[0] + (float)remf * fmaxf(D - (float)kth * dq, 0.0f);
        atomicAdd(d_out, total * (1.0f / ((float)NA * (float)KSEL)));
    }
}

extern "C" void kernel_launch(void* const* d_in, const int* in_sizes, int n_in,
                              void* d_out, int out_size, void* d_ws, size_t ws_size,
                              hipStream_t stream) {
    const float* o1 = (const float*)d_in[0];
    const float* o2 = (const float*)d_in[1];
    const int*   a1 = (const int*)d_in[2];
    const int*   a2 = (const int*)d_in[3];
    float* out = (float*)d_out;

    // ws layout from 16B-aligned end: [gmax 16B][ghist 1MB][q2 2.56MB][q1 2.56MB];
    // u16 distance rows from the base.
    const size_t qbytes = (size_t)NPTS * DIM;            // u8 rows
    const uintptr_t end = ((uintptr_t)d_ws + ws_size) & ~(uintptr_t)15;
    unsigned* gmax  = (unsigned*)(end - 16);
    unsigned* ghist = (unsigned*)(end - 16 - (size_t)NTASK * CBIN * 4);
    u8t*      q2    = (u8t*)((uintptr_t)ghist - qbytes);
    u8t*      q1    = (u8t*)((uintptr_t)q2 - qbytes);
    u16t*     wsd   = (u16t*)d_ws;

    const size_t dist_region = (uintptr_t)q1 - (uintptr_t)d_ws;
    int chunk = (int)(dist_region / ((size_t)NPTS * 2));
    chunk -= chunk % G;
    if (chunk < G) chunk = G;
    if (chunk > NTASK) chunk = NTASK;

    init_kernel<<<1024, 256, 0, stream>>>(out, ghist, gmax);
    maxabs_kernel<<<1024, 256, 0, stream>>>(o1, o2, gmax);
    quant_kernel<<<1280, 256, 0, stream>>>(o1, o2, q1, q2, gmax);

    for (int start = 0; start < NTASK; start += chunk) {
        int cur = NTASK - start;
        if (cur > chunk) cur = chunk;
        dim3 gd(cur / G, (NPTS + TILE - 1) / TILE);
        dist_kernel<<<gd, 256, 0, stream>>>(q1, q2, a1, a2, wsd, ghist, start);
        select_kernel<<<cur, 256, 0, stream>>>(o1, o2, a1, a2, wsd, ghist, gmax, start, out);
    }
}